// Round 5
// baseline (54.808 us; speedup 1.0000x reference)
//
#include <hip/hip_runtime.h>

// Problem constants (from reference setup_inputs): N=64, D=64, S=64, m=128
constexpr int N_ = 64;
constexpr int D_ = 64;
constexpr int S_ = 64;
constexpr int M_ = 128;

typedef float fv4 __attribute__((ext_vector_type(4)));

// out[n,s,i,j] = t4[n,s,i] + t3[n,s,j] + (t1[n,s,i]+t2[n,s])*(i==j)
//             + t5[n,s] + bias[s]
// One block per (n, s-pair): 2048 blocks, each computes the terms for two
// adjacent s (sharing the x[n] loads) and streams two 64 KiB tiles.
// Static vector-component indexing ONLY in the store loop (rule #20).
__global__ __launch_bounds__(256) void l12_fused2(
    const float* __restrict__ x,       // [N, D, M]
    const float* __restrict__ coeffs,  // [D, S, 5]
    const float* __restrict__ bias,    // [S]
    float* __restrict__ out)           // [N, S, M, M]
{
    const int blk = blockIdx.x;        // 0..2047
    const int n   = blk >> 5;          // / 32 pairs
    const int s0  = (blk & 31) * 2;    // s0, s0+1
    const int t   = threadIdx.x;       // 0..255
    const int i   = t & (M_ - 1);      // 0..127
    const int half = t >> 7;           // D-split (wave-uniform)

    __shared__ float part[2][5][2][M_];          // [sq][k][half][i] = 10 KiB
    __shared__ __align__(16) float A3[2][M_];
    __shared__ float CB[2][M_];
    __shared__ float DG[2][M_];
    __shared__ float wred[2][2][2];              // [sq][{t2,t5}][wave]

    // --- contraction: 5 dots for each of 2 s values, x loaded once --------
    float r[2][5];
    #pragma unroll
    for (int sq = 0; sq < 2; ++sq)
        #pragma unroll
        for (int k = 0; k < 5; ++k) r[sq][k] = 0.f;

    const float* xp = x + ((size_t)(n * D_) + half * (D_ / 2)) * M_ + i;
    #pragma unroll 8
    for (int dd = 0; dd < D_ / 2; ++dd) {
        float xv = xp[(size_t)dd * M_];           // coalesced, L2-resident
        int d = half * (D_ / 2) + dd;             // wave-uniform
        const float* cp = coeffs + ((size_t)d * S_ + s0) * 5;  // uniform -> s_load
        #pragma unroll
        for (int sq = 0; sq < 2; ++sq)
            #pragma unroll
            for (int k = 0; k < 5; ++k)
                r[sq][k] += cp[sq * 5 + k] * xv;
    }
    #pragma unroll
    for (int sq = 0; sq < 2; ++sq)
        #pragma unroll
        for (int k = 0; k < 5; ++k)
            part[sq][k][half][i] = r[sq][k];
    __syncthreads();

    // --- combine halves, reduce the two rank-1 scalars per s --------------
    float dg_pre[2], cb_pre[2];
    if (t < M_) {
        #pragma unroll
        for (int sq = 0; sq < 2; ++sq) {
            float a1 = part[sq][0][0][i] + part[sq][0][1][i];
            float a2 = part[sq][1][0][i] + part[sq][1][1][i];
            float a3 = part[sq][2][0][i] + part[sq][2][1][i];
            float a4 = part[sq][3][0][i] + part[sq][3][1][i];
            float a5 = part[sq][4][0][i] + part[sq][4][1][i];
            A3[sq][i] = a3;
            dg_pre[sq] = a1;
            cb_pre[sq] = a4;
            float v2 = a2, v5 = a5;
            #pragma unroll
            for (int off = 32; off; off >>= 1) {
                v2 += __shfl_down(v2, off);
                v5 += __shfl_down(v5, off);
            }
            if ((t & 63) == 0) {
                wred[sq][0][t >> 6] = v2;
                wred[sq][1][t >> 6] = v5;
            }
        }
    }
    __syncthreads();

    if (t < M_) {
        const float inv_m = 1.0f / (float)M_;
        #pragma unroll
        for (int sq = 0; sq < 2; ++sq) {
            DG[sq][i] = dg_pre[sq] + (wred[sq][0][0] + wred[sq][0][1]) * inv_m;
            CB[sq][i] = cb_pre[sq] + (wred[sq][1][0] + wred[sq][1][1]) * inv_m
                        + bias[s0 + sq];
        }
    }
    __syncthreads();

    // --- stream two 128x128 tiles, fully coalesced fv4 stores -------------
    float* outbase = out + (size_t)blk * 2 * (M_ * M_);
    const int j4 = (t & 31) * 4;

    #pragma unroll
    for (int sq = 0; sq < 2; ++sq) {
        fv4* outp = reinterpret_cast<fv4*>(outbase + (size_t)sq * (M_ * M_));
        const fv4 a3v = *reinterpret_cast<const fv4*>(&A3[sq][j4]);
        #pragma unroll
        for (int it = 0; it < 16; ++it) {
            int l   = it * 256 + t;      // fv4 index within tile
            int row = l >> 5;            // 32 fv4 per row
            float base = CB[sq][row];
            float dg   = DG[sq][row];
            fv4 v;
            v.x = base + a3v.x + ((row == j4 + 0) ? dg : 0.f);
            v.y = base + a3v.y + ((row == j4 + 1) ? dg : 0.f);
            v.z = base + a3v.z + ((row == j4 + 2) ? dg : 0.f);
            v.w = base + a3v.w + ((row == j4 + 3) ? dg : 0.f);
            outp[l] = v;                 // static indexing only
        }
    }
}

extern "C" void kernel_launch(void* const* d_in, const int* in_sizes, int n_in,
                              void* d_out, int out_size, void* d_ws, size_t ws_size,
                              hipStream_t stream) {
    const float* x      = (const float*)d_in[0];  // [64,64,128]
    const float* coeffs = (const float*)d_in[1];  // [64,64,5]
    const float* bias   = (const float*)d_in[2];  // [1,64,1,1] -> 64
    float* out          = (float*)d_out;          // [64,64,128,128]

    l12_fused2<<<dim3(N_ * S_ / 2), dim3(256), 0, stream>>>(x, coeffs, bias, out);
}

// Round 6
// 49.668 us; speedup vs baseline: 1.1035x; 1.1035x over previous
//
#include <hip/hip_runtime.h>

// Problem constants (from reference setup_inputs): N=64, D=64, S=64, m=128
constexpr int N_ = 64;
constexpr int D_ = 64;
constexpr int S_ = 64;
constexpr int M_ = 128;

typedef float fv4 __attribute__((ext_vector_type(4)));

// out[n,s,i,j] = t4[n,s,i] + t3[n,s,j] + (t1[n,s,i]+t2[n,s])*(i==j)
//             + t5[n,s] + bias[s]
// 2048 blocks; block (n0,s) handles tiles (n0,s) and (n0+32,s): same s ->
// coefficients staged once; tile-2 contraction overlaps tile-1 store drain
// (stores are issued, then the next barrier's vmcnt(0) lands after ~0.5us of
// contraction work). Per-tile phase bodies identical to the proven R3 kernel.
// Static vector-component indexing ONLY in the store loop (rule #20).
__global__ __launch_bounds__(256) void l12_fused2t(
    const float* __restrict__ x,       // [N, D, M]
    const float* __restrict__ coeffs,  // [D, S, 5]
    const float* __restrict__ bias,    // [S]
    float* __restrict__ out)           // [N, S, M, M]
{
    const int blk = blockIdx.x;        // 0..2047
    const int s   = blk & (S_ - 1);
    const int n0  = blk >> 6;          // 0..31
    const int t   = threadIdx.x;       // 0..255
    const int i   = t & (M_ - 1);      // 0..127
    const int half = t >> 7;           // D-split (wave-uniform)

    __shared__ float sh_c[D_][5];
    __shared__ float part[5][2][M_];
    __shared__ __align__(16) float A3[M_];
    __shared__ float CB[M_];
    __shared__ float DG[M_];
    __shared__ float wred[4];

    // Stage coeffs for this s ONCE (both tiles share s).
    if (t < D_) {
        const float* cp = coeffs + (t * S_ + s) * 5;
        #pragma unroll
        for (int k = 0; k < 5; ++k) sh_c[t][k] = cp[k];
    }
    const float bs = bias[s];
    __syncthreads();

    #pragma unroll 1
    for (int g = 0; g < 2; ++g) {
        const int n = n0 + g * 32;

        // --- five contractions over D, split 2-way across threads ---------
        float r0 = 0.f, r1 = 0.f, r2 = 0.f, r3 = 0.f, r4 = 0.f;
        const float* xp = x + ((size_t)(n * D_) + half * (D_ / 2)) * M_ + i;
        #pragma unroll
        for (int dd = 0; dd < D_ / 2; ++dd) {
            float xv = xp[(size_t)dd * M_];   // coalesced, L2-resident
            int d = half * (D_ / 2) + dd;
            r0 += sh_c[d][0] * xv;
            r1 += sh_c[d][1] * xv;
            r2 += sh_c[d][2] * xv;
            r3 += sh_c[d][3] * xv;
            r4 += sh_c[d][4] * xv;
        }
        part[0][half][i] = r0;
        part[1][half][i] = r1;
        part[2][half][i] = r2;
        part[3][half][i] = r3;
        part[4][half][i] = r4;
        __syncthreads();

        // --- combine halves + reduce the two rank-1 scalars ---------------
        if (t < M_) {
            float a1 = part[0][0][i] + part[0][1][i];
            float a2 = part[1][0][i] + part[1][1][i];
            float a3 = part[2][0][i] + part[2][1][i];
            float a4 = part[3][0][i] + part[3][1][i];
            float a5 = part[4][0][i] + part[4][1][i];
            A3[i] = a3;
            DG[i] = a1;    // + t2 added after reduction
            CB[i] = a4;    // + (t5 + bias) added after reduction

            float v2 = a2, v5 = a5;
            #pragma unroll
            for (int off = 32; off; off >>= 1) {
                v2 += __shfl_down(v2, off);
                v5 += __shfl_down(v5, off);
            }
            if ((t & 63) == 0) {
                wred[(t >> 6) * 2 + 0] = v2;
                wred[(t >> 6) * 2 + 1] = v5;
            }
        }
        __syncthreads();

        if (t < M_) {
            const float inv_m = 1.0f / (float)M_;
            DG[i] += (wred[0] + wred[2]) * inv_m;
            CB[i] += (wred[1] + wred[3]) * inv_m + bs;
        }
        __syncthreads();

        // --- stream the 128x128 tile, fully coalesced fv4 stores ----------
        fv4* outp = reinterpret_cast<fv4*>(
            out + ((size_t)n * S_ + s) * (M_ * M_));
        const int j4 = (t & 31) * 4;
        const fv4 a3v = *reinterpret_cast<const fv4*>(&A3[j4]);

        #pragma unroll
        for (int it = 0; it < 16; ++it) {
            int l   = it * 256 + t;      // fv4 index within tile (0..4095)
            int row = l >> 5;            // 32 fv4 per row
            float base = CB[row];
            float dg   = DG[row];
            fv4 v;
            v.x = base + a3v.x + ((row == j4 + 0) ? dg : 0.f);
            v.y = base + a3v.y + ((row == j4 + 1) ? dg : 0.f);
            v.z = base + a3v.z + ((row == j4 + 2) ? dg : 0.f);
            v.w = base + a3v.w + ((row == j4 + 3) ? dg : 0.f);
            outp[l] = v;                 // static indexing only
        }
        // no barrier here: next tile's contraction only writes part[] and
        // reads sh_c/x — stores drain under it; the post-contraction
        // __syncthreads provides the needed LDS ordering.
    }
}

extern "C" void kernel_launch(void* const* d_in, const int* in_sizes, int n_in,
                              void* d_out, int out_size, void* d_ws, size_t ws_size,
                              hipStream_t stream) {
    const float* x      = (const float*)d_in[0];  // [64,64,128]
    const float* coeffs = (const float*)d_in[1];  // [64,64,5]
    const float* bias   = (const float*)d_in[2];  // [1,64,1,1] -> 64
    float* out          = (float*)d_out;          // [64,64,128,128]

    l12_fused2t<<<dim3(N_ * S_ / 2), dim3(256), 0, stream>>>(x, coeffs, bias, out);
}